// Round 1
// baseline (2025.627 us; speedup 1.0000x reference)
//
#include <hip/hip_runtime.h>
#include <math.h>

// ---------------------------------------------------------------------------
// OneRecTokenizer fp32 baseline.
// Shapes: B=64 S=512 MM=1024 HID=512 T=4 NL=4 NHEAD=8 DH=64 RQ_L=3 CB=256
// Math restructuring:
//   scores[b,h,t,s] = (qh Wk^T)[b,h,t,c] · x[b,s,c]   (A-trick; bk drops out)
//   out[b,t,hd]     = (attn · x)[b,h,t,c] · Wv[c,hd] + bv  (U-trick)
// ---------------------------------------------------------------------------

struct Off { int p; long s1; long s2; };
__device__ __forceinline__ long zoff(Off o, int z) {
    return (long)(z / o.p) * o.s1 + (long)(z % o.p) * o.s2;
}

// Generic tiled fp32 GEMM: C = alpha * A(MxK) * B + bias, optional GELU.
// TB=false: B is [K,N] row-major (ldb). TB=true: B is [N,K] row-major (ldb).
// Batched over blockIdx.z with flexible offset rules (Off).
template<int BM, int BN, int BK, int TM, int TN, bool TB, int ACT>
__global__ __launch_bounds__(256)
void gemm_k(const float* __restrict__ Ag, const float* __restrict__ Bg,
            const float* __restrict__ biasg, float* __restrict__ Cg,
            int K, int lda, int ldb, int ldc, float alpha,
            Off oa, Off ob, Off oc, Off obias)
{
    constexpr int NT = (BM / TM) * (BN / TN);
    __shared__ float As[BK][BM + 4];
    __shared__ float Bs[BK][BN + 4];
    const int z  = blockIdx.z;
    const int n0 = blockIdx.x * BN;
    const float* A = Ag + zoff(oa, z) + (long)blockIdx.y * BM * lda;
    const float* B = Bg + zoff(ob, z);
    float*       C = Cg + zoff(oc, z) + (long)blockIdx.y * BM * ldc + n0;
    const int tid = threadIdx.x;
    const int tn  = tid % (BN / TN);
    const int tm  = tid / (BN / TN);

    float acc[TM][TN];
#pragma unroll
    for (int i = 0; i < TM; i++)
#pragma unroll
        for (int j = 0; j < TN; j++) acc[i][j] = 0.f;

    for (int k0 = 0; k0 < K; k0 += BK) {
        // ---- stage A tile (BM x BK), store transposed As[k][m]
        for (int t = tid; t < BM * BK / 4; t += NT) {
            int row = t / (BK / 4), kq = t % (BK / 4);
            float4 v = *(const float4*)(A + (long)row * lda + k0 + kq * 4);
            As[kq * 4 + 0][row] = v.x; As[kq * 4 + 1][row] = v.y;
            As[kq * 4 + 2][row] = v.z; As[kq * 4 + 3][row] = v.w;
        }
        // ---- stage B tile
        if constexpr (TB) {
            for (int t = tid; t < BN * BK / 4; t += NT) {
                int row = t / (BK / 4), kq = t % (BK / 4);   // row = n
                float4 v = *(const float4*)(B + (long)(n0 + row) * ldb + k0 + kq * 4);
                Bs[kq * 4 + 0][row] = v.x; Bs[kq * 4 + 1][row] = v.y;
                Bs[kq * 4 + 2][row] = v.z; Bs[kq * 4 + 3][row] = v.w;
            }
        } else {
            for (int t = tid; t < BK * BN / 4; t += NT) {
                int kk = t / (BN / 4), nq = t % (BN / 4);
                float4 v = *(const float4*)(B + (long)(k0 + kk) * ldb + n0 + nq * 4);
                *(float4*)(&Bs[kk][nq * 4]) = v;
            }
        }
        __syncthreads();
#pragma unroll
        for (int k = 0; k < BK; k++) {
            float a[TM], b[TN];
#pragma unroll
            for (int i = 0; i < TM; i++) a[i] = As[k][tm * TM + i];
#pragma unroll
            for (int j = 0; j < TN; j++) b[j] = Bs[k][tn * TN + j];
#pragma unroll
            for (int i = 0; i < TM; i++)
#pragma unroll
                for (int j = 0; j < TN; j++) acc[i][j] = fmaf(a[i], b[j], acc[i][j]);
        }
        __syncthreads();
    }
    long bof = biasg ? zoff(obias, z) : 0;
#pragma unroll
    for (int i = 0; i < TM; i++) {
#pragma unroll
        for (int j = 0; j < TN; j++) {
            float c = acc[i][j] * alpha;
            if (biasg) c += biasg[bof + n0 + tn * TN + j];
            if constexpr (ACT == 1) c = 0.5f * c * (1.f + erff(c * 0.70710678118654752f));
            C[(long)(tm * TM + i) * ldc + tn * TN + j] = c;
        }
    }
}

// ---- row softmax, width 512, one block (256 thr) per row -------------------
__global__ __launch_bounds__(256) void softmax512(float* __restrict__ s)
{
    __shared__ float red[4];
    const int tid = threadIdx.x;
    float* row = s + (long)blockIdx.x * 512;
    float v0 = row[tid], v1 = row[tid + 256];
    float m = fmaxf(v0, v1);
#pragma unroll
    for (int o = 32; o > 0; o >>= 1) m = fmaxf(m, __shfl_xor(m, o));
    if ((tid & 63) == 0) red[tid >> 6] = m;
    __syncthreads();
    m = fmaxf(fmaxf(red[0], red[1]), fmaxf(red[2], red[3]));
    __syncthreads();
    float e0 = expf(v0 - m), e1 = expf(v1 - m);
    float sum = e0 + e1;
#pragma unroll
    for (int o = 32; o > 0; o >>= 1) sum += __shfl_xor(sum, o);
    if ((tid & 63) == 0) red[tid >> 6] = sum;
    __syncthreads();
    sum = red[0] + red[1] + red[2] + red[3];
    float inv = 1.f / sum;
    row[tid] = e0 * inv; row[tid + 256] = e1 * inv;
}

// ---- q = LayerNorm(q + delta) * g + b, width 512, block per row ------------
__global__ __launch_bounds__(256) void add_ln(float* __restrict__ q,
                                              const float* __restrict__ d,
                                              const float* __restrict__ g,
                                              const float* __restrict__ b)
{
    __shared__ float red[4];
    const int tid = threadIdx.x;
    float* row = q + (long)blockIdx.x * 512;
    const float* dr = d + (long)blockIdx.x * 512;
    float v0 = row[tid] + dr[tid], v1 = row[tid + 256] + dr[tid + 256];
    float s = v0 + v1;
#pragma unroll
    for (int o = 32; o > 0; o >>= 1) s += __shfl_xor(s, o);
    if ((tid & 63) == 0) red[tid >> 6] = s;
    __syncthreads();
    float mu = (red[0] + red[1] + red[2] + red[3]) * (1.f / 512.f);
    __syncthreads();
    float c0 = v0 - mu, c1 = v1 - mu;
    float sq = c0 * c0 + c1 * c1;
#pragma unroll
    for (int o = 32; o > 0; o >>= 1) sq += __shfl_xor(sq, o);
    if ((tid & 63) == 0) red[tid >> 6] = sq;
    __syncthreads();
    float var = (red[0] + red[1] + red[2] + red[3]) * (1.f / 512.f);
    float rs = rsqrtf(var + 1e-5f);
    row[tid]       = c0 * rs * g[tid]       + b[tid];
    row[tid + 256] = c1 * rs * g[tid + 256] + b[tid + 256];
}

// ---- q[b*4+t][:] = query_tokens[t][:] --------------------------------------
__global__ __launch_bounds__(256) void bcast_q(const float* __restrict__ qt,
                                               float* __restrict__ q)
{
    const int r = blockIdx.x, tid = threadIdx.x, t = r & 3;
    q[(long)r * 512 + tid]       = qt[t * 512 + tid];
    q[(long)r * 512 + 256 + tid] = qt[t * 512 + 256 + tid];
}

// ---- codebook transpose + row norms: cbT[l][k][j], cn[l*256+j] -------------
__global__ __launch_bounds__(256) void cb_prep(const float* __restrict__ cb,
                                               float* __restrict__ cbT,
                                               float* __restrict__ cn)
{
    __shared__ float red[4];
    const int rowi = blockIdx.x;           // l*256 + j
    const int l = rowi >> 8, j = rowi & 255;
    const int tid = threadIdx.x;
    const float* row = cb + (long)rowi * 512;
    float v0 = row[tid], v1 = row[tid + 256];
    cbT[(long)l * 131072 + (long)tid * 256 + j]         = v0;
    cbT[(long)l * 131072 + (long)(tid + 256) * 256 + j] = v1;
    float s = v0 * v0 + v1 * v1;
#pragma unroll
    for (int o = 32; o > 0; o >>= 1) s += __shfl_xor(s, o);
    if ((tid & 63) == 0) red[tid >> 6] = s;
    __syncthreads();
    if (tid == 0) cn[rowi] = red[0] + red[1] + red[2] + red[3];
}

// ---- residual quantization: one block per point (b,t) ----------------------
__global__ __launch_bounds__(256) void rq_kernel(const float* __restrict__ qf,
                                                 const float* __restrict__ cb,
                                                 const float* __restrict__ cbT,
                                                 const float* __restrict__ cn,
                                                 float* __restrict__ out)
{
    __shared__ float r[512], rec[512];
    __shared__ float rd[4]; __shared__ int ri[4];
    __shared__ int sids[3];
    const int p = blockIdx.x, tid = threadIdx.x;
    r[tid]         = qf[(long)p * 512 + tid];
    r[tid + 256]   = qf[(long)p * 512 + 256 + tid];
    rec[tid] = 0.f; rec[tid + 256] = 0.f;
    __syncthreads();
    for (int l = 0; l < 3; l++) {
        const float* ct = cbT + (long)l * 131072;
        float dot = 0.f;
#pragma unroll 8
        for (int k = 0; k < 512; k++) dot = fmaf(r[k], ct[(long)k * 256 + tid], dot);
        // ||r||^2 is constant per point -> omitted (argmin unchanged)
        float d2 = cn[l * 256 + tid] - 2.f * dot;
        int idx = tid;
#pragma unroll
        for (int o = 32; o > 0; o >>= 1) {
            float od = __shfl_xor(d2, o); int oi = __shfl_xor(idx, o);
            if (od < d2 || (od == d2 && oi < idx)) { d2 = od; idx = oi; }
        }
        if ((tid & 63) == 0) { rd[tid >> 6] = d2; ri[tid >> 6] = idx; }
        __syncthreads();
        if (tid == 0) {
            float bd = rd[0]; int bb = ri[0];
            for (int w = 1; w < 4; w++)
                if (rd[w] < bd || (rd[w] == bd && ri[w] < bb)) { bd = rd[w]; bb = ri[w]; }
            sids[l] = bb;
        }
        __syncthreads();
        const float* crow = cb + ((long)l * 256 + sids[l]) * 512;
        float c0 = crow[tid], c1 = crow[tid + 256];
        r[tid] -= c0; rec[tid] += c0;
        r[tid + 256] -= c1; rec[tid + 256] += c1;
        __syncthreads();
    }
    float* orec = out + 768 + (long)p * 512;
    orec[tid] = rec[tid]; orec[tid + 256] = rec[tid + 256];
    if (tid < 3) out[p * 3 + tid] = (float)sids[tid];
}

// ---------------------------------------------------------------------------
extern "C" void kernel_launch(void* const* d_in, const int* in_sizes, int n_in,
                              void* d_out, int out_size, void* d_ws, size_t ws_size,
                              hipStream_t stream)
{
    const float* mm    = (const float*)d_in[0];
    const float* projW = (const float*)d_in[1];
    const float* projb = (const float*)d_in[2];
    const float* qt    = (const float*)d_in[3];
    const float* Wq    = (const float*)d_in[4];
    const float* bq    = (const float*)d_in[5];
    const float* Wk    = (const float*)d_in[6];
    // d_in[7] = bk: drops out of softmax (shift invariance) -> unused
    const float* Wv    = (const float*)d_in[8];
    const float* bv    = (const float*)d_in[9];
    const float* Wo    = (const float*)d_in[10];
    const float* bo    = (const float*)d_in[11];
    const float* W1    = (const float*)d_in[12];
    const float* b1    = (const float*)d_in[13];
    const float* W2    = (const float*)d_in[14];
    const float* b2    = (const float*)d_in[15];
    const float* lng   = (const float*)d_in[16];
    const float* lnb   = (const float*)d_in[17];
    const float* cbook = (const float*)d_in[18];

    float* ws   = (float*)d_ws;
    float* x    = ws;                    // [64*512, 512]     = 16,777,216
    float* q    = x    + 16777216;       // [256, 512]
    float* qh   = q    + 131072;         // [256, 512]
    float* Abuf = qh   + 131072;         // [64][32][512]     = 1,048,576
    float* sc   = Abuf + 1048576;        // [64][32][512]
    float* U    = sc   + 1048576;        // [64][32][512]
    float* cat  = U    + 1048576;        // [256, 512]
    float* tmp  = cat  + 131072;         // [256, 512]
    float* f1   = tmp  + 131072;         // [256, 2048]       = 524,288
    float* cbT  = f1   + 524288;         // [3][512][256]     = 393,216
    float* cn   = cbT  + 393216;         // 768

    const Off O0{1, 0, 0};

    // x = mm @ proj_W + proj_b   [32768,1024]x[1024,512]
    gemm_k<64,64,16,4,4,false,0><<<dim3(8, 512, 1), 256, 0, stream>>>(
        mm, projW, projb, x, 1024, 1024, 512, 512, 1.f, O0, O0, O0, O0);
    bcast_q<<<256, 256, 0, stream>>>(qt, q);
    cb_prep<<<768, 256, 0, stream>>>(cbook, cbT, cn);

    for (int i = 0; i < 4; i++) {
        const float* Wqi = Wq + (long)i * 262144; const float* bqi = bq + i * 512;
        const float* Wki = Wk + (long)i * 262144;
        const float* Wvi = Wv + (long)i * 262144; const float* bvi = bv + i * 512;
        const float* Woi = Wo + (long)i * 262144; const float* boi = bo + i * 512;
        const float* W1i = W1 + (long)i * 1048576; const float* b1i = b1 + i * 2048;
        const float* W2i = W2 + (long)i * 1048576; const float* b2i = b2 + i * 512;
        const float* gi  = lng + i * 512; const float* bi_ = lnb + i * 512;

        // qh = q @ Wq + bq
        gemm_k<64,64,16,4,4,false,0><<<dim3(8, 4, 1), 256, 0, stream>>>(
            q, Wqi, bqi, qh, 512, 512, 512, 512, 1.f, O0, O0, O0, O0);
        // A[b][h*4+t][c] = (1/8) qh[b4+t][h64+d] * Wk[c][h64+d]   (z = b*8+h)
        gemm_k<4,64,16,1,1,true,0><<<dim3(8, 1, 512), 256, 0, stream>>>(
            qh, Wki, nullptr, Abuf, 64, 512, 512, 512, 0.125f,
            Off{8, 2048, 64}, Off{8, 0, 64}, Off{1, 2048, 0}, O0);
        // scores[b][32][s] = A_b @ x_b^T   (z = b)
        gemm_k<32,64,16,2,4,true,0><<<dim3(8, 1, 64), 256, 0, stream>>>(
            Abuf, x, nullptr, sc, 512, 512, 512, 512, 1.f,
            Off{1, 16384, 0}, Off{1, 262144, 0}, Off{1, 16384, 0}, O0);
        softmax512<<<2048, 256, 0, stream>>>(sc);
        // U[b][32][c] = attn_b @ x_b   (z = b)
        gemm_k<32,64,16,2,4,false,0><<<dim3(8, 1, 64), 256, 0, stream>>>(
            sc, x, nullptr, U, 512, 512, 512, 512, 1.f,
            Off{1, 16384, 0}, Off{1, 262144, 0}, Off{1, 16384, 0}, O0);
        // cat[b4+t][h64+d] = U[b][h4+t][c] * Wv[c][h64+d] + bv   (z = b*8+h)
        gemm_k<4,64,16,1,1,false,0><<<dim3(1, 1, 512), 256, 0, stream>>>(
            U, Wvi, bvi, cat, 512, 512, 512, 512, 1.f,
            Off{1, 2048, 0}, Off{8, 0, 64}, Off{8, 2048, 64}, Off{8, 0, 64});
        // attn_out = cat @ Wo + bo
        gemm_k<64,64,16,4,4,false,0><<<dim3(8, 4, 1), 256, 0, stream>>>(
            cat, Woi, boi, tmp, 512, 512, 512, 512, 1.f, O0, O0, O0, O0);
        add_ln<<<256, 256, 0, stream>>>(q, tmp, gi, bi_);
        // ffn
        gemm_k<64,64,16,4,4,false,1><<<dim3(32, 4, 1), 256, 0, stream>>>(
            q, W1i, b1i, f1, 512, 512, 2048, 2048, 1.f, O0, O0, O0, O0);
        gemm_k<64,64,16,4,4,false,0><<<dim3(8, 4, 1), 256, 0, stream>>>(
            f1, W2i, b2i, tmp, 2048, 2048, 512, 512, 1.f, O0, O0, O0, O0);
        add_ln<<<256, 256, 0, stream>>>(q, tmp, gi, bi_);
    }

    rq_kernel<<<256, 256, 0, stream>>>(q, cbook, cbT, cn, (float*)d_out);
}

// Round 2
// 1648.948 us; speedup vs baseline: 1.2284x; 1.2284x over previous
//
#include <hip/hip_runtime.h>
#include <math.h>

// ---------------------------------------------------------------------------
// OneRecTokenizer. B=64 S=512 MM=1024 HID=512 T=4 NL=4 NHEAD=8 DH=64 RQ_L=3 CB=256
// Round 2: bf16x2-split (hi/lo) 3-pass MFMA for proj / scores / U.
//   A*B ~= Ahi*Bhi + Ahi*Blo + Alo*Bhi   (error ~2^-17 rel, keeps RQ argmins exact)
// ---------------------------------------------------------------------------

typedef __attribute__((ext_vector_type(8))) short   s16x8;
typedef __attribute__((ext_vector_type(8))) __bf16  bf16x8;
typedef __attribute__((ext_vector_type(4))) float   f32x4;

// split fp32 -> bf16 hi (truncated) + bf16 lo (RNE of remainder). err ~2^-17.
__device__ __forceinline__ void split2(float v, unsigned short& hi, unsigned short& lo) {
    unsigned u = __builtin_bit_cast(unsigned, v);
    hi = (unsigned short)(u >> 16);
    float hf = __builtin_bit_cast(float, u & 0xffff0000u);
    float l = v - hf;                       // exact in fp32
    unsigned ul = __builtin_bit_cast(unsigned, l);
    lo = (unsigned short)((ul + 0x7fffu + ((ul >> 16) & 1u)) >> 16);
}

__device__ __forceinline__ f32x4 mfma16(bf16x8 a, bf16x8 b, f32x4 c) {
    return __builtin_amdgcn_mfma_f32_16x16x32_bf16(a, b, c, 0, 0, 0);
}

struct Off { int p; long s1; long s2; };
__device__ __forceinline__ long zoff(Off o, int z) {
    return (long)(z / o.p) * o.s1 + (long)(z % o.p) * o.s2;
}

// ---------------------------------------------------------------------------
// bf16x2 3-pass MFMA GEMM:  C = A(MxK) @ BT(NxK)^T (+bias)
// A row-major [M][K]; BT row-major [N][K] (both hi/lo bf16, except PROJ: A fp32,
// split on the fly). PROJ epilogue: +bias, split output into two bf16 arrays.
// Non-PROJ epilogue: fp32 C. z-batched via strA/strB/strC element strides.
// LDS tiles [row][32] with slot swizzle s^f(r), f(r)=(r+(r>>2))&3 -> 2-way banks.
// ---------------------------------------------------------------------------
template<int BM, int BN, int FM, int FN, int WR, int WC, bool PROJ>
__global__ __launch_bounds__(256)
void mfma_gemm(const void* __restrict__ Ahi_, const void* __restrict__ Alo_,
               const unsigned short* __restrict__ BTh_, const unsigned short* __restrict__ BTl_,
               const float* __restrict__ bias,
               void* __restrict__ Chi_, void* __restrict__ Clo_,
               int K, int lda, int ldb, int ldc,
               long strA, long strB, long strC)
{
    static_assert(BN == 128 && WR * WC == 4, "layout");
    static_assert((PROJ && BM == 128) || (!PROJ && BM == 32), "staging path");
    __shared__ __align__(16) unsigned short sA[2][BM][32];
    __shared__ __align__(16) unsigned short sB[2][BN][32];

    const int tid = threadIdx.x;
    const int z   = blockIdx.z;
    const int m0  = blockIdx.y * BM;
    const int n0  = blockIdx.x * BN;
    const int lane = tid & 63, w = tid >> 6;
    const int wr = w / WC, wc = w % WC;

    const float* Af = nullptr;
    const unsigned short *Ah = nullptr, *Al = nullptr;
    if constexpr (PROJ) {
        Af = (const float*)Ahi_;
    } else {
        Ah = (const unsigned short*)Ahi_ + (long)z * strA;
        Al = (const unsigned short*)Alo_ + (long)z * strA;
    }
    const unsigned short* Bh = BTh_ + (long)z * strB;
    const unsigned short* Bl = BTl_ + (long)z * strB;

    f32x4 acc[FM][FN];
#pragma unroll
    for (int i = 0; i < FM; i++)
#pragma unroll
        for (int j = 0; j < FN; j++) acc[i][j] = f32x4{0.f, 0.f, 0.f, 0.f};

    for (int k0 = 0; k0 < K; k0 += 32) {
        __syncthreads();
        // ---- stage A tile
        if constexpr (PROJ) {
            const int r = tid >> 1, h = tid & 1;
            const int fs = (r + (r >> 2)) & 3;
            const float* src = Af + (long)(m0 + r) * lda + k0 + h * 16;
#pragma unroll
            for (int s2 = 0; s2 < 2; s2++) {
                const int s = 2 * h + s2;
                float4 v0 = *(const float4*)(src + s2 * 8);
                float4 v1 = *(const float4*)(src + s2 * 8 + 4);
                float vv[8] = {v0.x, v0.y, v0.z, v0.w, v1.x, v1.y, v1.z, v1.w};
                union { s16x8 v; unsigned short u[8]; } hh, ll;
#pragma unroll
                for (int j = 0; j < 8; j++) split2(vv[j], hh.u[j], ll.u[j]);
                *(s16x8*)&sA[0][r][(s ^ fs) * 8] = hh.v;
                *(s16x8*)&sA[1][r][(s ^ fs) * 8] = ll.v;
            }
        } else {
            const int p = tid >> 7;          // 0: hi, 1: lo
            const int c = tid & 127;
            const int r = c >> 2, s = c & 3;
            const int fs = (r + (r >> 2)) & 3;
            const unsigned short* src = (p ? Al : Ah) + (long)(m0 + r) * lda + k0 + s * 8;
            *(s16x8*)&sA[p][r][(s ^ fs) * 8] = *(const s16x8*)src;
        }
        // ---- stage B tile (128x32 per array, 1024 16B-chunks total)
#pragma unroll
        for (int i = 0; i < 4; i++) {
            const int c = tid + 256 * i;
            const int p = c >> 9;
            const int cc = c & 511;
            const int r = cc >> 2, s = cc & 3;
            const int fs = (r + (r >> 2)) & 3;
            const unsigned short* src = (p ? Bl : Bh) + (long)(n0 + r) * ldb + k0 + s * 8;
            *(s16x8*)&sB[p][r][(s ^ fs) * 8] = *(const s16x8*)src;
        }
        __syncthreads();
        // ---- fragments + 3-pass MFMA
        const int li = lane & 15, ks = lane >> 4;
        bf16x8 ah[FM], al[FM], bh[FN], bl[FN];
#pragma unroll
        for (int mi = 0; mi < FM; mi++) {
            const int r = wr * (FM * 16) + mi * 16 + li;
            const int fs = (r + (r >> 2)) & 3;
            ah[mi] = __builtin_bit_cast(bf16x8, *(const s16x8*)&sA[0][r][(ks ^ fs) * 8]);
            al[mi] = __builtin_bit_cast(bf16x8, *(const s16x8*)&sA[1][r][(ks ^ fs) * 8]);
        }
#pragma unroll
        for (int ni = 0; ni < FN; ni++) {
            const int r = wc * (FN * 16) + ni * 16 + li;
            const int fs = (r + (r >> 2)) & 3;
            bh[ni] = __builtin_bit_cast(bf16x8, *(const s16x8*)&sB[0][r][(ks ^ fs) * 8]);
            bl[ni] = __builtin_bit_cast(bf16x8, *(const s16x8*)&sB[1][r][(ks ^ fs) * 8]);
        }
#pragma unroll
        for (int mi = 0; mi < FM; mi++)
#pragma unroll
            for (int ni = 0; ni < FN; ni++) acc[mi][ni] = mfma16(ah[mi], bh[ni], acc[mi][ni]);
#pragma unroll
        for (int mi = 0; mi < FM; mi++)
#pragma unroll
            for (int ni = 0; ni < FN; ni++) acc[mi][ni] = mfma16(ah[mi], bl[ni], acc[mi][ni]);
#pragma unroll
        for (int mi = 0; mi < FM; mi++)
#pragma unroll
            for (int ni = 0; ni < FN; ni++) acc[mi][ni] = mfma16(al[mi], bh[ni], acc[mi][ni]);
    }
    // ---- epilogue (C/D: col = lane&15, row = (lane>>4)*4 + reg)
    if constexpr (PROJ) {
        unsigned short* xh = (unsigned short*)Chi_;
        unsigned short* xl = (unsigned short*)Clo_;
#pragma unroll
        for (int mi = 0; mi < FM; mi++)
#pragma unroll
            for (int r4 = 0; r4 < 4; r4++) {
                const int m = m0 + wr * (FM * 16) + mi * 16 + (lane >> 4) * 4 + r4;
#pragma unroll
                for (int ni = 0; ni < FN; ni++) {
                    const int n = n0 + wc * (FN * 16) + ni * 16 + (lane & 15);
                    float v = acc[mi][ni][r4] + bias[n];
                    unsigned short h, l; split2(v, h, l);
                    xh[(long)m * ldc + n] = h;
                    xl[(long)m * ldc + n] = l;
                }
            }
    } else {
        float* C = (float*)Chi_ + (long)z * strC;
#pragma unroll
        for (int mi = 0; mi < FM; mi++)
#pragma unroll
            for (int r4 = 0; r4 < 4; r4++) {
                const int m = m0 + wr * (FM * 16) + mi * 16 + (lane >> 4) * 4 + r4;
#pragma unroll
                for (int ni = 0; ni < FN; ni++) {
                    const int n = n0 + wc * (FN * 16) + ni * 16 + (lane & 15);
                    C[(long)m * ldc + n] = acc[mi][ni][r4];
                }
            }
    }
}

// ---- projW [1024][512] -> projWT hi/lo [512][1024] -------------------------
__global__ __launch_bounds__(256) void prep_wT(const float* __restrict__ W,
                                               unsigned short* __restrict__ Th,
                                               unsigned short* __restrict__ Tl)
{
    __shared__ float t[64][68];
    const int c0 = blockIdx.x * 64, k0 = blockIdx.y * 64;
    const int tid = threadIdx.x;
#pragma unroll
    for (int i = 0; i < 4; i++) {
        int ch = tid + 256 * i;
        int r = ch >> 4, q = ch & 15;
        float4 v = *(const float4*)(W + (long)(k0 + r) * 512 + c0 + q * 4);
        t[r][q * 4 + 0] = v.x; t[r][q * 4 + 1] = v.y;
        t[r][q * 4 + 2] = v.z; t[r][q * 4 + 3] = v.w;
    }
    __syncthreads();
#pragma unroll
    for (int i = 0; i < 4; i++) {
        int ch = tid + 256 * i;
        int rc = ch >> 4, qk = ch & 15;
        union { uint2 v; unsigned short u[4]; } oh, ol;
#pragma unroll
        for (int j = 0; j < 4; j++) split2(t[qk * 4 + j][rc], oh.u[j], ol.u[j]);
        *(uint2*)(Th + (long)(c0 + rc) * 1024 + k0 + qk * 4) = oh.v;
        *(uint2*)(Tl + (long)(c0 + rc) * 1024 + k0 + qk * 4) = ol.v;
    }
}

// ---- x hi/lo [b*s][c] -> xT hi/lo [b][c][s] --------------------------------
__global__ __launch_bounds__(256) void transpose_x(const unsigned short* __restrict__ xh,
                                                   const unsigned short* __restrict__ xl,
                                                   unsigned short* __restrict__ xTh,
                                                   unsigned short* __restrict__ xTl)
{
    __shared__ unsigned short th[64][72], tl[64][72];
    const int b = blockIdx.z, c0 = blockIdx.x * 64, s0 = blockIdx.y * 64;
    const int tid = threadIdx.x;
    const long ibase = ((long)b * 512 + s0) * 512 + c0;
#pragma unroll
    for (int i = 0; i < 2; i++) {
        int ch = tid + 256 * i;
        int r = ch >> 3, s = ch & 7;
        *(s16x8*)&th[r][s * 8] = *(const s16x8*)(xh + ibase + (long)r * 512 + s * 8);
        *(s16x8*)&tl[r][s * 8] = *(const s16x8*)(xl + ibase + (long)r * 512 + s * 8);
    }
    __syncthreads();
    const long obase = ((long)b * 512 + c0) * 512 + s0;
#pragma unroll
    for (int i = 0; i < 2; i++) {
        int ch = tid + 256 * i;
        int rc = ch >> 3, sc = ch & 7;
        union { s16x8 v; unsigned short u[8]; } oh, ol;
#pragma unroll
        for (int j = 0; j < 8; j++) { oh.u[j] = th[sc * 8 + j][rc]; ol.u[j] = tl[sc * 8 + j][rc]; }
        *(s16x8*)(xTh + obase + (long)rc * 512 + sc * 8) = oh.v;
        *(s16x8*)(xTl + obase + (long)rc * 512 + sc * 8) = ol.v;
    }
}

// ---------------------------------------------------------------------------
// Generic tiled fp32 GEMM (small/q-path ops). OUT: 0 fp32, 1 fp32+GELU,
// 2 split-bf16 (Cg=hi, Cg2=lo).
template<int BM, int BN, int BK, int TM, int TN, bool TB, int OUT>
__global__ __launch_bounds__(256)
void gemm_k(const float* __restrict__ Ag, const float* __restrict__ Bg,
            const float* __restrict__ biasg, void* __restrict__ Cg, void* __restrict__ Cg2,
            int K, int lda, int ldb, int ldc, float alpha,
            Off oa, Off ob, Off oc, Off obias)
{
    constexpr int NT = (BM / TM) * (BN / TN);
    __shared__ float As[BK][BM + 4];
    __shared__ float Bs[BK][BN + 4];
    const int z  = blockIdx.z;
    const int n0 = blockIdx.x * BN;
    const float* A = Ag + zoff(oa, z) + (long)blockIdx.y * BM * lda;
    const float* B = Bg + zoff(ob, z);
    const int tid = threadIdx.x;
    const int tn  = tid % (BN / TN);
    const int tm  = tid / (BN / TN);

    float acc[TM][TN];
#pragma unroll
    for (int i = 0; i < TM; i++)
#pragma unroll
        for (int j = 0; j < TN; j++) acc[i][j] = 0.f;

    for (int k0 = 0; k0 < K; k0 += BK) {
        for (int t = tid; t < BM * BK / 4; t += NT) {
            int row = t / (BK / 4), kq = t % (BK / 4);
            float4 v = *(const float4*)(A + (long)row * lda + k0 + kq * 4);
            As[kq * 4 + 0][row] = v.x; As[kq * 4 + 1][row] = v.y;
            As[kq * 4 + 2][row] = v.z; As[kq * 4 + 3][row] = v.w;
        }
        if constexpr (TB) {
            for (int t = tid; t < BN * BK / 4; t += NT) {
                int row = t / (BK / 4), kq = t % (BK / 4);
                float4 v = *(const float4*)(B + (long)(n0 + row) * ldb + k0 + kq * 4);
                Bs[kq * 4 + 0][row] = v.x; Bs[kq * 4 + 1][row] = v.y;
                Bs[kq * 4 + 2][row] = v.z; Bs[kq * 4 + 3][row] = v.w;
            }
        } else {
            for (int t = tid; t < BK * BN / 4; t += NT) {
                int kk = t / (BN / 4), nq = t % (BN / 4);
                float4 v = *(const float4*)(B + (long)(k0 + kk) * ldb + n0 + nq * 4);
                *(float4*)(&Bs[kk][nq * 4]) = v;
            }
        }
        __syncthreads();
#pragma unroll
        for (int k = 0; k < BK; k++) {
            float a[TM], b[TN];
#pragma unroll
            for (int i = 0; i < TM; i++) a[i] = As[k][tm * TM + i];
#pragma unroll
            for (int j = 0; j < TN; j++) b[j] = Bs[k][tn * TN + j];
#pragma unroll
            for (int i = 0; i < TM; i++)
#pragma unroll
                for (int j = 0; j < TN; j++) acc[i][j] = fmaf(a[i], b[j], acc[i][j]);
        }
        __syncthreads();
    }
    const long cbase = zoff(oc, z) + (long)blockIdx.y * BM * ldc + n0;
    const long bof = biasg ? zoff(obias, z) : 0;
#pragma unroll
    for (int i = 0; i < TM; i++) {
#pragma unroll
        for (int j = 0; j < TN; j++) {
            float c = acc[i][j] * alpha;
            if (biasg) c += biasg[bof + n0 + tn * TN + j];
            if constexpr (OUT == 1) c = 0.5f * c * (1.f + erff(c * 0.70710678118654752f));
            const long idx = cbase + (long)(tm * TM + i) * ldc + tn * TN + j;
            if constexpr (OUT == 2) {
                unsigned short h, l; split2(c, h, l);
                ((unsigned short*)Cg)[idx] = h;
                ((unsigned short*)Cg2)[idx] = l;
            } else {
                ((float*)Cg)[idx] = c;
            }
        }
    }
}

// ---- row softmax (width 512) with bf16x2-split output ----------------------
__global__ __launch_bounds__(256) void softmax_split(const float* __restrict__ sc,
                                                     unsigned short* __restrict__ Ph,
                                                     unsigned short* __restrict__ Pl)
{
    __shared__ float red[4];
    const int tid = threadIdx.x;
    const float* row = sc + (long)blockIdx.x * 512;
    float v0 = row[tid], v1 = row[tid + 256];
    float m = fmaxf(v0, v1);
#pragma unroll
    for (int o = 32; o > 0; o >>= 1) m = fmaxf(m, __shfl_xor(m, o));
    if ((tid & 63) == 0) red[tid >> 6] = m;
    __syncthreads();
    m = fmaxf(fmaxf(red[0], red[1]), fmaxf(red[2], red[3]));
    __syncthreads();
    float e0 = expf(v0 - m), e1 = expf(v1 - m);
    float sum = e0 + e1;
#pragma unroll
    for (int o = 32; o > 0; o >>= 1) sum += __shfl_xor(sum, o);
    if ((tid & 63) == 0) red[tid >> 6] = sum;
    __syncthreads();
    sum = red[0] + red[1] + red[2] + red[3];
    float inv = 1.f / sum;
    const long base = (long)blockIdx.x * 512;
    unsigned short h, l;
    split2(e0 * inv, h, l); Ph[base + tid] = h;       Pl[base + tid] = l;
    split2(e1 * inv, h, l); Ph[base + tid + 256] = h; Pl[base + tid + 256] = l;
}

// ---- q = LayerNorm(q + delta) * g + b --------------------------------------
__global__ __launch_bounds__(256) void add_ln(float* __restrict__ q,
                                              const float* __restrict__ d,
                                              const float* __restrict__ g,
                                              const float* __restrict__ b)
{
    __shared__ float red[4];
    const int tid = threadIdx.x;
    float* row = q + (long)blockIdx.x * 512;
    const float* dr = d + (long)blockIdx.x * 512;
    float v0 = row[tid] + dr[tid], v1 = row[tid + 256] + dr[tid + 256];
    float s = v0 + v1;
#pragma unroll
    for (int o = 32; o > 0; o >>= 1) s += __shfl_xor(s, o);
    if ((tid & 63) == 0) red[tid >> 6] = s;
    __syncthreads();
    float mu = (red[0] + red[1] + red[2] + red[3]) * (1.f / 512.f);
    __syncthreads();
    float c0 = v0 - mu, c1 = v1 - mu;
    float sq = c0 * c0 + c1 * c1;
#pragma unroll
    for (int o = 32; o > 0; o >>= 1) sq += __shfl_xor(sq, o);
    if ((tid & 63) == 0) red[tid >> 6] = sq;
    __syncthreads();
    float var = (red[0] + red[1] + red[2] + red[3]) * (1.f / 512.f);
    float rs = rsqrtf(var + 1e-5f);
    row[tid]       = c0 * rs * g[tid]       + b[tid];
    row[tid + 256] = c1 * rs * g[tid + 256] + b[tid + 256];
}

__global__ __launch_bounds__(256) void bcast_q(const float* __restrict__ qt,
                                               float* __restrict__ q)
{
    const int r = blockIdx.x, tid = threadIdx.x, t = r & 3;
    q[(long)r * 512 + tid]       = qt[t * 512 + tid];
    q[(long)r * 512 + 256 + tid] = qt[t * 512 + 256 + tid];
}

__global__ __launch_bounds__(256) void cb_prep(const float* __restrict__ cb,
                                               float* __restrict__ cbT,
                                               float* __restrict__ cn)
{
    __shared__ float red[4];
    const int rowi = blockIdx.x;
    const int l = rowi >> 8, j = rowi & 255;
    const int tid = threadIdx.x;
    const float* row = cb + (long)rowi * 512;
    float v0 = row[tid], v1 = row[tid + 256];
    cbT[(long)l * 131072 + (long)tid * 256 + j]         = v0;
    cbT[(long)l * 131072 + (long)(tid + 256) * 256 + j] = v1;
    float s = v0 * v0 + v1 * v1;
#pragma unroll
    for (int o = 32; o > 0; o >>= 1) s += __shfl_xor(s, o);
    if ((tid & 63) == 0) red[tid >> 6] = s;
    __syncthreads();
    if (tid == 0) cn[rowi] = red[0] + red[1] + red[2] + red[3];
}

__global__ __launch_bounds__(256) void rq_kernel(const float* __restrict__ qf,
                                                 const float* __restrict__ cb,
                                                 const float* __restrict__ cbT,
                                                 const float* __restrict__ cn,
                                                 float* __restrict__ out)
{
    __shared__ float r[512], rec[512];
    __shared__ float rd[4]; __shared__ int ri[4];
    __shared__ int sids[3];
    const int p = blockIdx.x, tid = threadIdx.x;
    r[tid]         = qf[(long)p * 512 + tid];
    r[tid + 256]   = qf[(long)p * 512 + 256 + tid];
    rec[tid] = 0.f; rec[tid + 256] = 0.f;
    __syncthreads();
    for (int l = 0; l < 3; l++) {
        const float* ct = cbT + (long)l * 131072;
        float dot = 0.f;
#pragma unroll 8
        for (int k = 0; k < 512; k++) dot = fmaf(r[k], ct[(long)k * 256 + tid], dot);
        float d2 = cn[l * 256 + tid] - 2.f * dot;
        int idx = tid;
#pragma unroll
        for (int o = 32; o > 0; o >>= 1) {
            float od = __shfl_xor(d2, o); int oi = __shfl_xor(idx, o);
            if (od < d2 || (od == d2 && oi < idx)) { d2 = od; idx = oi; }
        }
        if ((tid & 63) == 0) { rd[tid >> 6] = d2; ri[tid >> 6] = idx; }
        __syncthreads();
        if (tid == 0) {
            float bd = rd[0]; int bb = ri[0];
            for (int w = 1; w < 4; w++)
                if (rd[w] < bd || (rd[w] == bd && ri[w] < bb)) { bd = rd[w]; bb = ri[w]; }
            sids[l] = bb;
        }
        __syncthreads();
        const float* crow = cb + ((long)l * 256 + sids[l]) * 512;
        float c0 = crow[tid], c1 = crow[tid + 256];
        r[tid] -= c0; rec[tid] += c0;
        r[tid + 256] -= c1; rec[tid + 256] += c1;
        __syncthreads();
    }
    float* orec = out + 768 + (long)p * 512;
    orec[tid] = rec[tid]; orec[tid + 256] = rec[tid + 256];
    if (tid < 3) out[p * 3 + tid] = (float)sids[tid];
}

// ---------------------------------------------------------------------------
extern "C" void kernel_launch(void* const* d_in, const int* in_sizes, int n_in,
                              void* d_out, int out_size, void* d_ws, size_t ws_size,
                              hipStream_t stream)
{
    const float* mm    = (const float*)d_in[0];
    const float* projW = (const float*)d_in[1];
    const float* projb = (const float*)d_in[2];
    const float* qt    = (const float*)d_in[3];
    const float* Wq    = (const float*)d_in[4];
    const float* bq    = (const float*)d_in[5];
    const float* Wk    = (const float*)d_in[6];
    const float* Wv    = (const float*)d_in[8];
    const float* bv    = (const float*)d_in[9];
    const float* Wo    = (const float*)d_in[10];
    const float* bo    = (const float*)d_in[11];
    const float* W1    = (const float*)d_in[12];
    const float* b1    = (const float*)d_in[13];
    const float* W2    = (const float*)d_in[14];
    const float* b2    = (const float*)d_in[15];
    const float* lng   = (const float*)d_in[16];
    const float* lnb   = (const float*)d_in[17];
    const float* cbook = (const float*)d_in[18];

    char* p = (char*)d_ws;
    auto alloc = [&](size_t bytes) { char* r = p; p += (bytes + 255) & ~(size_t)255; return r; };
    unsigned short* x_h   = (unsigned short*)alloc(16777216ull * 2);
    unsigned short* x_l   = (unsigned short*)alloc(16777216ull * 2);
    unsigned short* xT_h  = (unsigned short*)alloc(16777216ull * 2);
    unsigned short* xT_l  = (unsigned short*)alloc(16777216ull * 2);
    unsigned short* pwT_h = (unsigned short*)alloc(524288ull * 2);
    unsigned short* pwT_l = (unsigned short*)alloc(524288ull * 2);
    unsigned short* A_h   = (unsigned short*)alloc(1048576ull * 2);
    unsigned short* A_l   = (unsigned short*)alloc(1048576ull * 2);
    unsigned short* P_h   = (unsigned short*)alloc(1048576ull * 2);
    unsigned short* P_l   = (unsigned short*)alloc(1048576ull * 2);
    float* sc  = (float*)alloc(1048576ull * 4);
    float* U   = (float*)alloc(1048576ull * 4);
    float* q   = (float*)alloc(131072ull * 4);
    float* qh  = (float*)alloc(131072ull * 4);
    float* cat = (float*)alloc(131072ull * 4);
    float* tmp = (float*)alloc(131072ull * 4);
    float* f1  = (float*)alloc(524288ull * 4);
    float* cbT = (float*)alloc(393216ull * 4);
    float* cn  = (float*)alloc(768ull * 4);

    const Off O0{1, 0, 0};

    // projWT hi/lo
    prep_wT<<<dim3(8, 16), 256, 0, stream>>>(projW, pwT_h, pwT_l);
    // x = mm @ projW + projb  (MFMA bf16x2, split output)
    mfma_gemm<128, 128, 4, 4, 2, 2, true><<<dim3(4, 256, 1), 256, 0, stream>>>(
        mm, nullptr, pwT_h, pwT_l, projb, x_h, x_l, 1024, 1024, 1024, 512, 0, 0, 0);
    transpose_x<<<dim3(8, 8, 64), 256, 0, stream>>>(x_h, x_l, xT_h, xT_l);
    bcast_q<<<256, 256, 0, stream>>>(qt, q);
    cb_prep<<<768, 256, 0, stream>>>(cbook, cbT, cn);

    for (int i = 0; i < 4; i++) {
        const float* Wqi = Wq + (long)i * 262144; const float* bqi = bq + i * 512;
        const float* Wki = Wk + (long)i * 262144;
        const float* Wvi = Wv + (long)i * 262144; const float* bvi = bv + i * 512;
        const float* Woi = Wo + (long)i * 262144; const float* boi = bo + i * 512;
        const float* W1i = W1 + (long)i * 1048576; const float* b1i = b1 + i * 2048;
        const float* W2i = W2 + (long)i * 1048576; const float* b2i = b2 + i * 512;
        const float* gi  = lng + i * 512; const float* bi_ = lnb + i * 512;

        // qh = q @ Wq + bq  (fp32)
        gemm_k<64, 64, 16, 4, 4, false, 0><<<dim3(8, 4, 1), 256, 0, stream>>>(
            q, Wqi, bqi, qh, nullptr, 512, 512, 512, 512, 1.f, O0, O0, O0, O0);
        // A[b][h*4+t][c] = (1/8) qh_head @ Wk_head^T  (fp32 -> split bf16)
        gemm_k<4, 64, 16, 1, 1, true, 2><<<dim3(8, 1, 512), 256, 0, stream>>>(
            qh, Wki, nullptr, A_h, A_l, 64, 512, 512, 512, 0.125f,
            Off{8, 2048, 64}, Off{8, 0, 64}, Off{1, 2048, 0}, O0);
        // scores[b][32][s] = A_b @ x_b^T  (MFMA)
        mfma_gemm<32, 128, 2, 2, 1, 4, false><<<dim3(4, 1, 64), 256, 0, stream>>>(
            A_h, A_l, x_h, x_l, nullptr, sc, nullptr, 512, 512, 512, 512,
            16384, 262144, 16384);
        softmax_split<<<2048, 256, 0, stream>>>(sc, P_h, P_l);
        // U[b][32][c] = P_b @ x_b  (MFMA, B = xT)
        mfma_gemm<32, 128, 2, 2, 1, 4, false><<<dim3(4, 1, 64), 256, 0, stream>>>(
            P_h, P_l, xT_h, xT_l, nullptr, U, nullptr, 512, 512, 512, 512,
            16384, 262144, 16384);
        // cat[b4+t][h64+d] = U_head @ Wv_head + bv  (fp32)
        gemm_k<4, 64, 16, 1, 1, false, 0><<<dim3(1, 1, 512), 256, 0, stream>>>(
            U, Wvi, bvi, cat, nullptr, 512, 512, 512, 512, 1.f,
            Off{1, 2048, 0}, Off{8, 0, 64}, Off{8, 2048, 64}, Off{8, 0, 64});
        // attn_out = cat @ Wo + bo
        gemm_k<64, 64, 16, 4, 4, false, 0><<<dim3(8, 4, 1), 256, 0, stream>>>(
            cat, Woi, boi, tmp, nullptr, 512, 512, 512, 512, 1.f, O0, O0, O0, O0);
        add_ln<<<256, 256, 0, stream>>>(q, tmp, gi, bi_);
        // ffn
        gemm_k<64, 64, 16, 4, 4, false, 1><<<dim3(32, 4, 1), 256, 0, stream>>>(
            q, W1i, b1i, f1, nullptr, 512, 512, 2048, 2048, 1.f, O0, O0, O0, O0);
        gemm_k<64, 64, 16, 4, 4, false, 0><<<dim3(8, 4, 1), 256, 0, stream>>>(
            f1, W2i, b2i, tmp, nullptr, 2048, 2048, 512, 512, 1.f, O0, O0, O0, O0);
        add_ln<<<256, 256, 0, stream>>>(q, tmp, gi, bi_);
    }

    rq_kernel<<<256, 256, 0, stream>>>(q, cbook, cbT, cn, (float*)d_out);
}

// Round 3
// 1259.437 us; speedup vs baseline: 1.6084x; 1.3093x over previous
//
#include <hip/hip_runtime.h>
#include <math.h>

// ---------------------------------------------------------------------------
// OneRecTokenizer. B=64 S=512 MM=1024 HID=512 T=4 NL=4 NHEAD=8 DH=64 RQ_L=3 CB=256
// Round 3: everything GEMM-shaped on MFMA via bf16x2 (hi/lo) 3-pass split.
//   A*B ~= Ah*Bh + Ah*Bl + Al*Bh  (rel err ~2^-17)
// Weight folding: MT = (1/8)Wq·Wk^T per head (A = q·MT + biasA),
//                 WVOT = Wv·Wo per head (out = U·WVOT + (bv·Wo+bo)).
// proj: XCD-chunked swizzle so the 4 N-blocks of an M-panel share L2.
// ---------------------------------------------------------------------------

typedef __attribute__((ext_vector_type(8))) short   s16x8;
typedef __attribute__((ext_vector_type(8))) __bf16  bf16x8;
typedef __attribute__((ext_vector_type(4))) float   f32x4;

__device__ __forceinline__ void split2(float v, unsigned short& hi, unsigned short& lo) {
    unsigned u = __builtin_bit_cast(unsigned, v);
    hi = (unsigned short)(u >> 16);
    float hf = __builtin_bit_cast(float, u & 0xffff0000u);
    float l = v - hf;
    unsigned ul = __builtin_bit_cast(unsigned, l);
    lo = (unsigned short)((ul + 0x7fffu + ((ul >> 16) & 1u)) >> 16);
}

__device__ __forceinline__ f32x4 mfma16(bf16x8 a, bf16x8 b, f32x4 c) {
    return __builtin_amdgcn_mfma_f32_16x16x32_bf16(a, b, c, 0, 0, 0);
}

// ---------------------------------------------------------------------------
// Unified bf16x2 3-pass MFMA GEMM. BN=128 fixed. out[m,n] = sum_k A[m,k]*BT[n,k].
// AMODE 0: A = split bf16 pair (Ah_,Al_), BM=32. AMODE 1: A fp32, split on the
// fly, BM=128. OMODE 0: fp32 out. OMODE 1: split-bf16 out (Ch_,Cl_).
// IDX 0: z*strC + m*ldc + n   (plain)
// IDX 1: A-scatter  [b][h*4+t][c] from (m=bt, n=h*512+c)
// IDX 2: U-scatter  [b*4+t][h*512+c] from (z=b, m=h*4+t, n=c)
// LDS slot swizzle s^fs, fs=(r+(r>>2))&3 -> 2-way (free) banks everywhere.
// ---------------------------------------------------------------------------
template<int BM, int FM, int FN, int WR, int WC, int AMODE, int OMODE, int IDX,
         bool GELU, bool SWZ>
__global__ __launch_bounds__(256)
void mfma_gemm(const void* __restrict__ Ah_, const void* __restrict__ Al_,
               const unsigned short* __restrict__ Bh_, const unsigned short* __restrict__ Bl_,
               const float* __restrict__ bias,
               void* __restrict__ Ch_, void* __restrict__ Cl_,
               int K, int lda, int ldb, int ldc,
               long strA, long strB, long strC)
{
    __shared__ __align__(16) unsigned short sA[2][BM][32];
    __shared__ __align__(16) unsigned short sB[2][128][32];

    int bx = blockIdx.x, by = blockIdx.y;
    if constexpr (SWZ) {                      // XCD-chunked remap (nb % 8 == 0)
        int nb = gridDim.x * gridDim.y;
        int h  = bx + gridDim.x * by;
        int orig = (h & 7) * (nb >> 3) + (h >> 3);
        bx = orig % gridDim.x; by = orig / gridDim.x;
    }
    const int tid = threadIdx.x, z = blockIdx.z;
    const int m0 = by * BM, n0 = bx * 128;
    const int lane = tid & 63, w = tid >> 6;
    const int wr = w / WC, wc = w % WC;

    const float* Af = nullptr;
    const unsigned short *Ah = nullptr, *Al = nullptr;
    if constexpr (AMODE == 1) {
        Af = (const float*)Ah_;
    } else {
        Ah = (const unsigned short*)Ah_ + (long)z * strA;
        Al = (const unsigned short*)Al_ + (long)z * strA;
    }
    const unsigned short* Bh = Bh_ + (long)z * strB;
    const unsigned short* Bl = Bl_ + (long)z * strB;

    f32x4 acc[FM][FN];
#pragma unroll
    for (int i = 0; i < FM; i++)
#pragma unroll
        for (int j = 0; j < FN; j++) acc[i][j] = f32x4{0.f, 0.f, 0.f, 0.f};

    for (int k0 = 0; k0 < K; k0 += 32) {
        __syncthreads();
        // ---- stage A (conflict-free: 16 rows x 4 slots per wave = 1KB span)
        if constexpr (AMODE == 1) {
#pragma unroll
            for (int i = 0; i < BM / 64; i++) {           // BM=128 -> 2
                const int c = tid + 256 * i;
                const int r = c >> 2, s = c & 3;
                const int fs = (r + (r >> 2)) & 3;
                const float* src = Af + (long)(m0 + r) * lda + k0 + s * 8;
                float4 v0 = *(const float4*)src;
                float4 v1 = *(const float4*)(src + 4);
                float vv[8] = {v0.x, v0.y, v0.z, v0.w, v1.x, v1.y, v1.z, v1.w};
                union { s16x8 v; unsigned short u[8]; } hh, ll;
#pragma unroll
                for (int j = 0; j < 8; j++) split2(vv[j], hh.u[j], ll.u[j]);
                *(s16x8*)&sA[0][r][(s ^ fs) * 8] = hh.v;
                *(s16x8*)&sA[1][r][(s ^ fs) * 8] = ll.v;
            }
        } else {                                          // BM=32: 256 chunks
            const int p = tid >> 7;
            const int c = tid & 127;
            const int r = c >> 2, s = c & 3;
            const int fs = (r + (r >> 2)) & 3;
            const unsigned short* src = (p ? Al : Ah) + (long)(m0 + r) * lda + k0 + s * 8;
            *(s16x8*)&sA[p][r][(s ^ fs) * 8] = *(const s16x8*)src;
        }
        // ---- stage B (128x32 hi + lo)
#pragma unroll
        for (int i = 0; i < 4; i++) {
            const int c = tid + 256 * i;
            const int p = c >> 9;
            const int cc = c & 511;
            const int r = cc >> 2, s = cc & 3;
            const int fs = (r + (r >> 2)) & 3;
            const unsigned short* src = (p ? Bl : Bh) + (long)(n0 + r) * ldb + k0 + s * 8;
            *(s16x8*)&sB[p][r][(s ^ fs) * 8] = *(const s16x8*)src;
        }
        __syncthreads();
        // ---- fragments + 3-pass MFMA
        const int li = lane & 15, ks = lane >> 4;
        bf16x8 ah[FM], al[FM], bh[FN], bl[FN];
#pragma unroll
        for (int mi = 0; mi < FM; mi++) {
            const int r = wr * (FM * 16) + mi * 16 + li;
            const int fs = (r + (r >> 2)) & 3;
            ah[mi] = __builtin_bit_cast(bf16x8, *(const s16x8*)&sA[0][r][(ks ^ fs) * 8]);
            al[mi] = __builtin_bit_cast(bf16x8, *(const s16x8*)&sA[1][r][(ks ^ fs) * 8]);
        }
#pragma unroll
        for (int ni = 0; ni < FN; ni++) {
            const int r = wc * (FN * 16) + ni * 16 + li;
            const int fs = (r + (r >> 2)) & 3;
            bh[ni] = __builtin_bit_cast(bf16x8, *(const s16x8*)&sB[0][r][(ks ^ fs) * 8]);
            bl[ni] = __builtin_bit_cast(bf16x8, *(const s16x8*)&sB[1][r][(ks ^ fs) * 8]);
        }
#pragma unroll
        for (int mi = 0; mi < FM; mi++)
#pragma unroll
            for (int ni = 0; ni < FN; ni++) acc[mi][ni] = mfma16(ah[mi], bh[ni], acc[mi][ni]);
#pragma unroll
        for (int mi = 0; mi < FM; mi++)
#pragma unroll
            for (int ni = 0; ni < FN; ni++) acc[mi][ni] = mfma16(ah[mi], bl[ni], acc[mi][ni]);
#pragma unroll
        for (int mi = 0; mi < FM; mi++)
#pragma unroll
            for (int ni = 0; ni < FN; ni++) acc[mi][ni] = mfma16(al[mi], bh[ni], acc[mi][ni]);
    }
    // ---- epilogue (C/D: col = lane&15, row = (lane>>4)*4 + reg)
#pragma unroll
    for (int mi = 0; mi < FM; mi++)
#pragma unroll
        for (int r4 = 0; r4 < 4; r4++) {
            const int m = m0 + wr * (FM * 16) + mi * 16 + (lane >> 4) * 4 + r4;
#pragma unroll
            for (int ni = 0; ni < FN; ni++) {
                const int n = n0 + wc * (FN * 16) + ni * 16 + (lane & 15);
                float v = acc[mi][ni][r4];
                if (bias) v += bias[n];
                if constexpr (GELU) v = 0.5f * v * (1.f + erff(v * 0.70710678118654752f));
                long id;
                if constexpr (IDX == 0)      id = (long)z * strC + (long)m * ldc + n;
                else if constexpr (IDX == 1) id = ((long)(m >> 2)) * 16384
                                                + (long)((n >> 9) * 4 + (m & 3)) * 512 + (n & 511);
                else                         id = ((long)z * 4 + (m & 3)) * 4096
                                                + (long)(m >> 2) * 512 + n;
                if constexpr (OMODE == 1) {
                    unsigned short h, l; split2(v, h, l);
                    ((unsigned short*)Ch_)[id] = h;
                    ((unsigned short*)Cl_)[id] = l;
                } else {
                    ((float*)Ch_)[id] = v;
                }
            }
        }
}

// ---------------------------------------------------------------------------
// Both-operands-fp32 split MFMA, K=64 (head dim): out[m,n] = scale*sum_d A[m,d]B[n,d]
// A_z = A + (z/8)*zsA + (z%8)*64 (row stride 512); same for B. Split-bf16 out at
// (z/8)*S1 + (z%8)*S2 + m*SM + n.  M=N=512, BM=BN=128, grid (4,4,Z).
// ---------------------------------------------------------------------------
__global__ __launch_bounds__(256)
void w2gemm(const float* __restrict__ A_, const float* __restrict__ B_,
            float scale, unsigned short* __restrict__ Th, unsigned short* __restrict__ Tl,
            long zsA, long zsB, long S1, long S2, long SM)
{
    __shared__ __align__(16) unsigned short sA[2][128][32];
    __shared__ __align__(16) unsigned short sB[2][128][32];
    const int tid = threadIdx.x, z = blockIdx.z;
    const int m0 = blockIdx.y * 128, n0 = blockIdx.x * 128;
    const int lane = tid & 63, w = tid >> 6, wr = w >> 1, wc = w & 1;
    const float* Ab = A_ + (long)(z >> 3) * zsA + (z & 7) * 64;
    const float* Bb = B_ + (long)(z >> 3) * zsB + (z & 7) * 64;

    f32x4 acc[4][4];
#pragma unroll
    for (int i = 0; i < 4; i++)
#pragma unroll
        for (int j = 0; j < 4; j++) acc[i][j] = f32x4{0.f, 0.f, 0.f, 0.f};

    for (int k0 = 0; k0 < 64; k0 += 32) {
        __syncthreads();
#pragma unroll
        for (int op = 0; op < 2; op++) {
            const float* src0 = op ? Bb : Ab;
            auto* dst = op ? sB : sA;
#pragma unroll
            for (int i = 0; i < 2; i++) {
                const int c = tid + 256 * i;
                const int r = c >> 2, s = c & 3;
                const int fs = (r + (r >> 2)) & 3;
                const float* src = src0 + (long)((op ? n0 : m0) + r) * 512 + k0 + s * 8;
                float4 v0 = *(const float4*)src;
                float4 v1 = *(const float4*)(src + 4);
                float vv[8] = {v0.x, v0.y, v0.z, v0.w, v1.x, v1.y, v1.z, v1.w};
                union { s16x8 v; unsigned short u[8]; } hh, ll;
#pragma unroll
                for (int j = 0; j < 8; j++) split2(vv[j], hh.u[j], ll.u[j]);
                *(s16x8*)&dst[0][r][(s ^ fs) * 8] = hh.v;
                *(s16x8*)&dst[1][r][(s ^ fs) * 8] = ll.v;
            }
        }
        __syncthreads();
        const int li = lane & 15, ks = lane >> 4;
        bf16x8 ah[4], al[4], bh[4], bl[4];
#pragma unroll
        for (int mi = 0; mi < 4; mi++) {
            const int r = wr * 64 + mi * 16 + li;
            const int fs = (r + (r >> 2)) & 3;
            ah[mi] = __builtin_bit_cast(bf16x8, *(const s16x8*)&sA[0][r][(ks ^ fs) * 8]);
            al[mi] = __builtin_bit_cast(bf16x8, *(const s16x8*)&sA[1][r][(ks ^ fs) * 8]);
        }
#pragma unroll
        for (int ni = 0; ni < 4; ni++) {
            const int r = wc * 64 + ni * 16 + li;
            const int fs = (r + (r >> 2)) & 3;
            bh[ni] = __builtin_bit_cast(bf16x8, *(const s16x8*)&sB[0][r][(ks ^ fs) * 8]);
            bl[ni] = __builtin_bit_cast(bf16x8, *(const s16x8*)&sB[1][r][(ks ^ fs) * 8]);
        }
#pragma unroll
        for (int mi = 0; mi < 4; mi++)
#pragma unroll
            for (int ni = 0; ni < 4; ni++) acc[mi][ni] = mfma16(ah[mi], bh[ni], acc[mi][ni]);
#pragma unroll
        for (int mi = 0; mi < 4; mi++)
#pragma unroll
            for (int ni = 0; ni < 4; ni++) acc[mi][ni] = mfma16(ah[mi], bl[ni], acc[mi][ni]);
#pragma unroll
        for (int mi = 0; mi < 4; mi++)
#pragma unroll
            for (int ni = 0; ni < 4; ni++) acc[mi][ni] = mfma16(al[mi], bh[ni], acc[mi][ni]);
    }
#pragma unroll
    for (int mi = 0; mi < 4; mi++)
#pragma unroll
        for (int r4 = 0; r4 < 4; r4++) {
            const int m = m0 + wr * 64 + mi * 16 + (lane >> 4) * 4 + r4;
#pragma unroll
            for (int ni = 0; ni < 4; ni++) {
                const int n = n0 + wc * 64 + ni * 16 + (lane & 15);
                float v = acc[mi][ni][r4] * scale;
                unsigned short h, l; split2(v, h, l);
                long id = (long)(z >> 3) * S1 + (long)(z & 7) * S2 + (long)m * SM + n;
                Th[id] = h; Tl[id] = l;
            }
        }
}

// ---- fp32 [K][N] -> split-bf16 [N][K], z-batched ---------------------------
__global__ __launch_bounds__(256)
void prep_split_T(const float* __restrict__ in, unsigned short* __restrict__ Th,
                  unsigned short* __restrict__ Tl, int ldin, int ldo,
                  long inStride, long outStride)
{
    __shared__ float t[64][68];
    const int n0 = blockIdx.x * 64, k0 = blockIdx.y * 64;
    const int z = blockIdx.z, tid = threadIdx.x;
    const float* src = in + (long)z * inStride;
#pragma unroll
    for (int i = 0; i < 4; i++) {
        int ch = tid + 256 * i;
        int r = ch >> 4, q = ch & 15;
        float4 v = *(const float4*)(src + (long)(k0 + r) * ldin + n0 + q * 4);
        t[r][q * 4 + 0] = v.x; t[r][q * 4 + 1] = v.y;
        t[r][q * 4 + 2] = v.z; t[r][q * 4 + 3] = v.w;
    }
    __syncthreads();
#pragma unroll
    for (int i = 0; i < 4; i++) {
        int ch = tid + 256 * i;
        int rc = ch >> 4, qk = ch & 15;
        union { uint2 v; unsigned short u[4]; } oh, ol;
#pragma unroll
        for (int j = 0; j < 4; j++) split2(t[qk * 4 + j][rc], oh.u[j], ol.u[j]);
        long o = (long)z * outStride + (long)(n0 + rc) * ldo + k0 + qk * 4;
        *(uint2*)(Th + o) = oh.v;
        *(uint2*)(Tl + o) = ol.v;
    }
}

// ---- fp32 [512][512] transpose, z-batched ----------------------------------
__global__ __launch_bounds__(256)
void transpose32(const float* __restrict__ in, float* __restrict__ out, long zstr)
{
    __shared__ float t[64][65];
    const int c0 = blockIdx.x * 64, r0 = blockIdx.y * 64;
    const int z = blockIdx.z, tid = threadIdx.x;
#pragma unroll
    for (int i = 0; i < 4; i++) {
        int ch = tid + 256 * i;
        int r = ch >> 4, q = ch & 15;
        float4 v = *(const float4*)(in + (long)z * zstr + (long)(r0 + r) * 512 + c0 + q * 4);
        t[r][q * 4 + 0] = v.x; t[r][q * 4 + 1] = v.y;
        t[r][q * 4 + 2] = v.z; t[r][q * 4 + 3] = v.w;
    }
    __syncthreads();
#pragma unroll
    for (int i = 0; i < 4; i++) {
        int ch = tid + 256 * i;
        int rc = ch >> 4, qk = ch & 15;
        float4 o;
        o.x = t[qk * 4 + 0][rc]; o.y = t[qk * 4 + 1][rc];
        o.z = t[qk * 4 + 2][rc]; o.w = t[qk * 4 + 3][rc];
        *(float4*)(out + (long)z * zstr + (long)(c0 + rc) * 512 + r0 + qk * 4) = o;
    }
}

// ---- x hi/lo [b*s][c] -> xT hi/lo [b][c][s] --------------------------------
__global__ __launch_bounds__(256) void transpose_x(const unsigned short* __restrict__ xh,
                                                   const unsigned short* __restrict__ xl,
                                                   unsigned short* __restrict__ xTh,
                                                   unsigned short* __restrict__ xTl)
{
    __shared__ unsigned short th[64][72], tl[64][72];
    const int b = blockIdx.z, c0 = blockIdx.x * 64, s0 = blockIdx.y * 64;
    const int tid = threadIdx.x;
    const long ibase = ((long)b * 512 + s0) * 512 + c0;
#pragma unroll
    for (int i = 0; i < 2; i++) {
        int ch = tid + 256 * i;
        int r = ch >> 3, s = ch & 7;
        *(s16x8*)&th[r][s * 8] = *(const s16x8*)(xh + ibase + (long)r * 512 + s * 8);
        *(s16x8*)&tl[r][s * 8] = *(const s16x8*)(xl + ibase + (long)r * 512 + s * 8);
    }
    __syncthreads();
    const long obase = ((long)b * 512 + c0) * 512 + s0;
#pragma unroll
    for (int i = 0; i < 2; i++) {
        int ch = tid + 256 * i;
        int rc = ch >> 3, sc = ch & 7;
        union { s16x8 v; unsigned short u[8]; } oh, ol;
#pragma unroll
        for (int j = 0; j < 8; j++) { oh.u[j] = th[sc * 8 + j][rc]; ol.u[j] = tl[sc * 8 + j][rc]; }
        *(s16x8*)(xTh + obase + (long)rc * 512 + sc * 8) = oh.v;
        *(s16x8*)(xTl + obase + (long)rc * 512 + sc * 8) = ol.v;
    }
}

// ---- biasA[l][h*512+c] = 0.125 * sum_d bq[l,hd]*Wk[l,c,hd] -----------------
__global__ __launch_bounds__(256) void biasA_k(const float* __restrict__ bq,
                                               const float* __restrict__ Wk,
                                               float* __restrict__ biasA)
{
    const int gid = blockIdx.x * 256 + threadIdx.x;     // 16384
    const int l = gid >> 12, hc = gid & 4095, h = hc >> 9, c = hc & 511;
    const float* b = bq + l * 512 + h * 64;
    const float* w = Wk + (long)l * 262144 + (long)c * 512 + h * 64;
    float s = 0.f;
#pragma unroll 16
    for (int d = 0; d < 64; d++) s = fmaf(b[d], w[d], s);
    biasA[gid] = 0.125f * s;
}

// ---- biasO[l][o] = sum_j bv[l,j]*Wo[l,j,o] + bo[l,o] -----------------------
__global__ __launch_bounds__(256) void biasO_k(const float* __restrict__ bv,
                                               const float* __restrict__ Wo,
                                               const float* __restrict__ bo,
                                               float* __restrict__ biasO)
{
    __shared__ float sbv[512];
    const int l = blockIdx.x, tid = threadIdx.x;
    sbv[tid] = bv[l * 512 + tid];
    sbv[tid + 256] = bv[l * 512 + tid + 256];
    __syncthreads();
#pragma unroll
    for (int half = 0; half < 2; half++) {
        const int o = tid + half * 256;
        float s = bo[l * 512 + o];
        const float* w = Wo + (long)l * 262144 + o;
        for (int j = 0; j < 512; j++) s = fmaf(sbv[j], w[(long)j * 512], s);
        biasO[l * 512 + o] = s;
    }
}

// ---- row softmax (width 512) with split output -----------------------------
__global__ __launch_bounds__(256) void softmax_split(const float* __restrict__ sc,
                                                     unsigned short* __restrict__ Ph,
                                                     unsigned short* __restrict__ Pl)
{
    __shared__ float red[4];
    const int tid = threadIdx.x;
    const float* row = sc + (long)blockIdx.x * 512;
    float v0 = row[tid], v1 = row[tid + 256];
    float m = fmaxf(v0, v1);
#pragma unroll
    for (int o = 32; o > 0; o >>= 1) m = fmaxf(m, __shfl_xor(m, o));
    if ((tid & 63) == 0) red[tid >> 6] = m;
    __syncthreads();
    m = fmaxf(fmaxf(red[0], red[1]), fmaxf(red[2], red[3]));
    __syncthreads();
    float e0 = expf(v0 - m), e1 = expf(v1 - m);
    float sum = e0 + e1;
#pragma unroll
    for (int o = 32; o > 0; o >>= 1) sum += __shfl_xor(sum, o);
    if ((tid & 63) == 0) red[tid >> 6] = sum;
    __syncthreads();
    sum = red[0] + red[1] + red[2] + red[3];
    float inv = 1.f / sum;
    const long base = (long)blockIdx.x * 512;
    unsigned short h, l;
    split2(e0 * inv, h, l); Ph[base + tid] = h;       Pl[base + tid] = l;
    split2(e1 * inv, h, l); Ph[base + tid + 256] = h; Pl[base + tid + 256] = l;
}

// ---- q = LayerNorm(q + delta)*g + b; also emit split q ---------------------
__global__ __launch_bounds__(256) void add_ln(float* __restrict__ q,
                                              const float* __restrict__ d,
                                              const float* __restrict__ g,
                                              const float* __restrict__ b,
                                              unsigned short* __restrict__ qh_s,
                                              unsigned short* __restrict__ ql_s)
{
    __shared__ float red[4];
    const int tid = threadIdx.x;
    const long base = (long)blockIdx.x * 512;
    float* row = q + base;
    const float* dr = d + base;
    float v0 = row[tid] + dr[tid], v1 = row[tid + 256] + dr[tid + 256];
    float s = v0 + v1;
#pragma unroll
    for (int o = 32; o > 0; o >>= 1) s += __shfl_xor(s, o);
    if ((tid & 63) == 0) red[tid >> 6] = s;
    __syncthreads();
    float mu = (red[0] + red[1] + red[2] + red[3]) * (1.f / 512.f);
    __syncthreads();
    float c0 = v0 - mu, c1 = v1 - mu;
    float sq = c0 * c0 + c1 * c1;
#pragma unroll
    for (int o = 32; o > 0; o >>= 1) sq += __shfl_xor(sq, o);
    if ((tid & 63) == 0) red[tid >> 6] = sq;
    __syncthreads();
    float var = (red[0] + red[1] + red[2] + red[3]) * (1.f / 512.f);
    float rs = rsqrtf(var + 1e-5f);
    float o0 = c0 * rs * g[tid] + b[tid];
    float o1 = c1 * rs * g[tid + 256] + b[tid + 256];
    row[tid] = o0; row[tid + 256] = o1;
    unsigned short h, l;
    split2(o0, h, l); qh_s[base + tid] = h;       ql_s[base + tid] = l;
    split2(o1, h, l); qh_s[base + tid + 256] = h; ql_s[base + tid + 256] = l;
}

// ---- q init: broadcast query_tokens, fp32 + split --------------------------
__global__ __launch_bounds__(256) void bcast_q(const float* __restrict__ qt,
                                               float* __restrict__ q,
                                               unsigned short* __restrict__ qh_s,
                                               unsigned short* __restrict__ ql_s)
{
    const int r = blockIdx.x, tid = threadIdx.x, t = r & 3;
    const long base = (long)r * 512;
    float a = qt[t * 512 + tid], c = qt[t * 512 + 256 + tid];
    q[base + tid] = a; q[base + 256 + tid] = c;
    unsigned short h, l;
    split2(a, h, l); qh_s[base + tid] = h;       ql_s[base + tid] = l;
    split2(c, h, l); qh_s[base + tid + 256] = h; ql_s[base + tid + 256] = l;
}

__global__ __launch_bounds__(256) void cb_prep(const float* __restrict__ cb,
                                               float* __restrict__ cbT,
                                               float* __restrict__ cn)
{
    __shared__ float red[4];
    const int rowi = blockIdx.x;
    const int l = rowi >> 8, j = rowi & 255;
    const int tid = threadIdx.x;
    const float* row = cb + (long)rowi * 512;
    float v0 = row[tid], v1 = row[tid + 256];
    cbT[(long)l * 131072 + (long)tid * 256 + j]         = v0;
    cbT[(long)l * 131072 + (long)(tid + 256) * 256 + j] = v1;
    float s = v0 * v0 + v1 * v1;
#pragma unroll
    for (int o = 32; o > 0; o >>= 1) s += __shfl_xor(s, o);
    if ((tid & 63) == 0) red[tid >> 6] = s;
    __syncthreads();
    if (tid == 0) cn[rowi] = red[0] + red[1] + red[2] + red[3];
}

__global__ __launch_bounds__(256) void rq_kernel(const float* __restrict__ qf,
                                                 const float* __restrict__ cb,
                                                 const float* __restrict__ cbT,
                                                 const float* __restrict__ cn,
                                                 float* __restrict__ out)
{
    __shared__ float r[512], rec[512];
    __shared__ float rd[4]; __shared__ int ri[4];
    __shared__ int sids[3];
    const int p = blockIdx.x, tid = threadIdx.x;
    r[tid]         = qf[(long)p * 512 + tid];
    r[tid + 256]   = qf[(long)p * 512 + 256 + tid];
    rec[tid] = 0.f; rec[tid + 256] = 0.f;
    __syncthreads();
    for (int l = 0; l < 3; l++) {
        const float* ct = cbT + (long)l * 131072;
        float dot = 0.f;
#pragma unroll 8
        for (int k = 0; k < 512; k++) dot = fmaf(r[k], ct[(long)k * 256 + tid], dot);
        float d2 = cn[l * 256 + tid] - 2.f * dot;
        int idx = tid;
#pragma unroll
        for (int o = 32; o > 0; o >>= 1) {
            float od = __shfl_xor(d2, o); int oi = __shfl_xor(idx, o);
            if (od < d2 || (od == d2 && oi < idx)) { d2 = od; idx = oi; }
        }
        if ((tid & 63) == 0) { rd[tid >> 6] = d2; ri[tid >> 6] = idx; }
        __syncthreads();
        if (tid == 0) {
            float bd = rd[0]; int bb = ri[0];
            for (int w = 1; w < 4; w++)
                if (rd[w] < bd || (rd[w] == bd && ri[w] < bb)) { bd = rd[w]; bb = ri[w]; }
            sids[l] = bb;
        }
        __syncthreads();
        const float* crow = cb + ((long)l * 256 + sids[l]) * 512;
        float c0 = crow[tid], c1 = crow[tid + 256];
        r[tid] -= c0; rec[tid] += c0;
        r[tid + 256] -= c1; rec[tid + 256] += c1;
        __syncthreads();
    }
    float* orec = out + 768 + (long)p * 512;
    orec[tid] = rec[tid]; orec[tid + 256] = rec[tid + 256];
    if (tid < 3) out[p * 3 + tid] = (float)sids[tid];
}

// ---------------------------------------------------------------------------
extern "C" void kernel_launch(void* const* d_in, const int* in_sizes, int n_in,
                              void* d_out, int out_size, void* d_ws, size_t ws_size,
                              hipStream_t stream)
{
    const float* mm    = (const float*)d_in[0];
    const float* projW = (const float*)d_in[1];
    const float* projb = (const float*)d_in[2];
    const float* qt    = (const float*)d_in[3];
    const float* Wq    = (const float*)d_in[4];
    const float* bq    = (const float*)d_in[5];
    const float* Wk    = (const float*)d_in[6];
    const float* Wv    = (const float*)d_in[8];
    const float* bv    = (const float*)d_in[9];
    const float* Wo    = (const float*)d_in[10];
    const float* bo    = (const float*)d_in[11];
    const float* W1    = (const float*)d_in[12];
    const float* b1    = (const float*)d_in[13];
    const float* W2    = (const float*)d_in[14];
    const float* b2    = (const float*)d_in[15];
    const float* lng   = (const float*)d_in[16];
    const float* lnb   = (const float*)d_in[17];
    const float* cbook = (const float*)d_in[18];

    char* p = (char*)d_ws;
    auto alloc = [&](size_t bytes) { char* r = p; p += (bytes + 255) & ~(size_t)255; return r; };
    unsigned short* x_h   = (unsigned short*)alloc(16777216ull * 2);
    unsigned short* x_l   = (unsigned short*)alloc(16777216ull * 2);
    unsigned short* xT_h  = (unsigned short*)alloc(16777216ull * 2);
    unsigned short* xT_l  = (unsigned short*)alloc(16777216ull * 2);
    unsigned short* pwT_h = (unsigned short*)alloc(524288ull * 2);
    unsigned short* pwT_l = (unsigned short*)alloc(524288ull * 2);
    unsigned short* MT_h  = (unsigned short*)alloc(8388608ull * 2);
    unsigned short* MT_l  = (unsigned short*)alloc(8388608ull * 2);
    unsigned short* WVOT_h= (unsigned short*)alloc(8388608ull * 2);
    unsigned short* WVOT_l= (unsigned short*)alloc(8388608ull * 2);
    float*          WoT   = (float*)alloc(1048576ull * 4);
    unsigned short* W1T_h = (unsigned short*)alloc(4194304ull * 2);
    unsigned short* W1T_l = (unsigned short*)alloc(4194304ull * 2);
    unsigned short* W2T_h = (unsigned short*)alloc(4194304ull * 2);
    unsigned short* W2T_l = (unsigned short*)alloc(4194304ull * 2);
    unsigned short* A_h   = (unsigned short*)alloc(1048576ull * 2);
    unsigned short* A_l   = (unsigned short*)alloc(1048576ull * 2);
    unsigned short* P_h   = (unsigned short*)alloc(1048576ull * 2);
    unsigned short* P_l   = (unsigned short*)alloc(1048576ull * 2);
    unsigned short* U_h   = (unsigned short*)alloc(1048576ull * 2);
    unsigned short* U_l   = (unsigned short*)alloc(1048576ull * 2);
    unsigned short* f1_h  = (unsigned short*)alloc(524288ull * 2);
    unsigned short* f1_l  = (unsigned short*)alloc(524288ull * 2);
    unsigned short* q_h   = (unsigned short*)alloc(131072ull * 2);
    unsigned short* q_l   = (unsigned short*)alloc(131072ull * 2);
    float* sc    = (float*)alloc(1048576ull * 4);
    float* q     = (float*)alloc(131072ull * 4);
    float* tmp   = (float*)alloc(131072ull * 4);
    float* cbT   = (float*)alloc(393216ull * 4);
    float* cn    = (float*)alloc(768ull * 4);
    float* biasA = (float*)alloc(16384ull * 4);
    float* biasO = (float*)alloc(2048ull * 4);

    // ---- one-time weight prep ----
    prep_split_T<<<dim3(8, 16, 1), 256, 0, stream>>>(projW, pwT_h, pwT_l, 512, 1024, 0, 0);
    prep_split_T<<<dim3(32, 8, 4), 256, 0, stream>>>(W1, W1T_h, W1T_l, 2048, 512, 1048576, 1048576);
    prep_split_T<<<dim3(8, 32, 4), 256, 0, stream>>>(W2, W2T_h, W2T_l, 512, 2048, 1048576, 1048576);
    transpose32<<<dim3(8, 8, 4), 256, 0, stream>>>(Wo, WoT, 262144);
    // MT[l][h*512+c][k] = (1/8) sum_d Wk[l,c,hd]*Wq[l,k,hd]
    w2gemm<<<dim3(4, 4, 32), 256, 0, stream>>>(Wk, Wq, 0.125f, MT_h, MT_l,
        262144, 262144, 2097152, 262144, 512);
    // WVOT[l][o][h*512+c] = sum_d WoT[l,o,hd]*Wv[l,c,hd]
    w2gemm<<<dim3(4, 4, 32), 256, 0, stream>>>(WoT, Wv, 1.f, WVOT_h, WVOT_l,
        262144, 262144, 2097152, 512, 4096);
    biasA_k<<<64, 256, 0, stream>>>(bq, Wk, biasA);
    biasO_k<<<4, 256, 0, stream>>>(bv, Wo, bo, biasO);
    cb_prep<<<768, 256, 0, stream>>>(cbook, cbT, cn);
    bcast_q<<<256, 256, 0, stream>>>(qt, q, q_h, q_l);

    // ---- x = mm @ projW + projb (split out), then xT ----
    mfma_gemm<128, 4, 4, 2, 2, 1, 1, 0, false, true><<<dim3(4, 256, 1), 256, 0, stream>>>(
        mm, nullptr, pwT_h, pwT_l, projb, x_h, x_l, 1024, 1024, 1024, 512, 0, 0, 0);
    transpose_x<<<dim3(8, 8, 64), 256, 0, stream>>>(x_h, x_l, xT_h, xT_l);

    for (int i = 0; i < 4; i++) {
        const unsigned short* MTh = MT_h + (long)i * 2097152;
        const unsigned short* MTl = MT_l + (long)i * 2097152;
        const unsigned short* WVh = WVOT_h + (long)i * 2097152;
        const unsigned short* WVl = WVOT_l + (long)i * 2097152;
        const unsigned short* W1h = W1T_h + (long)i * 1048576;
        const unsigned short* W1l = W1T_l + (long)i * 1048576;
        const unsigned short* W2h = W2T_h + (long)i * 1048576;
        const unsigned short* W2l = W2T_l + (long)i * 1048576;
        const float* b1i = b1 + i * 2048; const float* b2i = b2 + i * 512;
        const float* gi  = lng + i * 512; const float* bi_ = lnb + i * 512;

        // A[b][ht][c] = q @ MT + biasA   (M=256, N=4096, K=512)
        mfma_gemm<32, 2, 2, 1, 4, 0, 1, 1, false, false><<<dim3(32, 8, 1), 256, 0, stream>>>(
            q_h, q_l, MTh, MTl, biasA + i * 4096, A_h, A_l, 512, 512, 512, 0, 0, 0, 0);
        // scores[b][32][s] = A_b @ x_b^T
        mfma_gemm<32, 2, 2, 1, 4, 0, 0, 0, false, false><<<dim3(4, 1, 64), 256, 0, stream>>>(
            A_h, A_l, x_h, x_l, nullptr, sc, nullptr, 512, 512, 512, 512,
            16384, 262144, 16384);
        softmax_split<<<2048, 256, 0, stream>>>(sc, P_h, P_l);
        // U[bt][h*512+c] = P_b @ x_b   (split out, U-scatter)
        mfma_gemm<32, 2, 2, 1, 4, 0, 1, 2, false, false><<<dim3(4, 1, 64), 256, 0, stream>>>(
            P_h, P_l, xT_h, xT_l, nullptr, U_h, U_l, 512, 512, 512, 0,
            16384, 262144, 0);
        // attn_out = U @ WVOT + biasO   (M=256, N=512, K=4096)
        mfma_gemm<32, 2, 2, 1, 4, 0, 0, 0, false, false><<<dim3(4, 8, 1), 256, 0, stream>>>(
            U_h, U_l, WVh, WVl, biasO + i * 512, tmp, nullptr, 4096, 4096, 4096, 512, 0, 0, 0);
        add_ln<<<256, 256, 0, stream>>>(q, tmp, gi, bi_, q_h, q_l);
        // ffn1: f1 = gelu(q @ W1 + b1)  (split out)
        mfma_gemm<32, 2, 2, 1, 4, 0, 1, 0, true, false><<<dim3(16, 8, 1), 256, 0, stream>>>(
            q_h, q_l, W1h, W1l, b1i, f1_h, f1_l, 512, 512, 512, 2048, 0, 0, 0);
        // ffn2: tmp = f1 @ W2 + b2
        mfma_gemm<32, 2, 2, 1, 4, 0, 0, 0, false, false><<<dim3(4, 8, 1), 256, 0, stream>>>(
            f1_h, f1_l, W2h, W2l, b2i, tmp, nullptr, 2048, 2048, 2048, 512, 0, 0, 0);
        add_ln<<<256, 256, 0, stream>>>(q, tmp, gi, bi_, q_h, q_l);
    }

    rq_kernel<<<256, 256, 0, stream>>>(q, cbook, cbT, cn, (float*)d_out);
}